// Round 11
// baseline (74.113 us; speedup 1.0000x reference)
//
#include <hip/hip_runtime.h>
#include <hip/hip_bf16.h>
#include <math.h>

#define NB      64      // batch
#define NNODES  1023    // 2*512-1
#define LC      20      // L*C = 5*4
#define DIN     512
#define NROWS   (NB * NNODES)   // 65472 = 1023 * 64 exactly
#define ET_PAD  404     // 400 + 4 pad

#define BM      64              // rows per gemm block (grid 1023)
#define SCP     21              // epilogue scratch stride

typedef unsigned short u16;
typedef short bf16x8 __attribute__((ext_vector_type(8)));
typedef float f32x4  __attribute__((ext_vector_type(4)));

__device__ __forceinline__ u16 f2bf(float f) {   // RNE f32 -> bf16 bits
    unsigned x = __float_as_uint(f);
    return (u16)((x + 0x7FFFu + ((x >> 16) & 1u)) >> 16);
}

// ---------------------------------------------------------------------------
// prep: ET (exp(trans) reindexed) + B fragments, compact layout (1280 uint4):
//  [0,1024):   nf=0 full:   idx = cg*64 + lane -> W[cg*32+(lane>>4)*8+j][lane&15]
//  [1024,1280): nf=1 compact: idx = 1024 + cg*16 + g*4 + c -> W[cg*32+g*8+j][16+c]
//  (cg = k-chunk 0..15, chunk = 32 k)
// ---------------------------------------------------------------------------
__global__ __launch_bounds__(256) void prep_kernel(
    const float* __restrict__ trans, const float* __restrict__ W,
    float* __restrict__ ET, u16* __restrict__ Bfrag)
{
    int t = blockIdx.x * 256 + threadIdx.x;
    if (t < 8000) {
        int q   = t % 20;
        int rem = t / 20;
        int j   = rem % 20;
        int i   = rem / 20;
        int ll = i >> 2, cl = i & 3;
        int lr = j >> 2, cr = j & 3;
        int lp = q >> 2, cp = q & 3;
        int src = ((((lp * 5 + ll) * 5 + lr) * 4 + cp) * 4 + cl) * 4 + cr;
        ET[q * ET_PAD + i * 20 + j] = expf(trans[src]);
    }
    if (t < 1280) {
        int col, kb;
        if (t < 1024) {
            int lane = t & 63, cg = t >> 6;
            col = lane & 15;
            kb  = cg * 32 + ((lane >> 4) & 3) * 8;
        } else {
            int idx = t - 1024;
            int cg = idx >> 4, g = (idx >> 2) & 3, c = idx & 3;
            col = 16 + c;
            kb  = cg * 32 + g * 8;
        }
        unsigned e[8];
        #pragma unroll
        for (int j = 0; j < 8; ++j)
            e[j] = (unsigned)f2bf(W[(kb + j) * LC + col]);
        uint4 v;
        v.x = e[0] | (e[1] << 16); v.y = e[2] | (e[3] << 16);
        v.z = e[4] | (e[5] << 16); v.w = e[6] | (e[7] << 16);
        ((uint4*)Bfrag)[t] = v;
    }
}

// ---------------------------------------------------------------------------
// gemm via mfma_f32_16x16x32_bf16, ZERO staging: each lane loads its own
// A-fragment (row lane&15, k contiguous (lane>>4)*8..+8) straight from h
// with one base pointer + immediate offsets. Per-wave independent stream —
// no barriers in the K-loop; compiler emits counted vmcnt per use.
// B: compact fragments in LDS (ds ops, off the vmcnt FIFO).
// Wave wv owns rows [wv*16, wv*16+16); 16 chunks of k=32; 2-deep pipeline.
// ---------------------------------------------------------------------------
__global__ __launch_bounds__(256, 5) void gemm_kernel(
    const float* __restrict__ h, const u16* __restrict__ Bfrag,
    const float* __restrict__ bias, float* __restrict__ buf)
{
    __shared__ uint4 Bs[1280];          // 20 KB B fragments
    __shared__ float scT[BM * SCP];     // 5.25 KB epilogue transpose
    const int t    = threadIdx.x;
    const int lane = t & 63;
    const int wv   = t >> 6;
    const size_t row0 = (size_t)blockIdx.x * BM;

    // B fragments -> LDS first (their ds_write waits retire only B loads)
    Bs[t] = ((const uint4*)Bfrag)[t];
    Bs[t + 256] = ((const uint4*)Bfrag)[t + 256];
    Bs[t + 512] = ((const uint4*)Bfrag)[t + 512];
    Bs[t + 768] = ((const uint4*)Bfrag)[t + 768];
    Bs[t + 1024] = ((const uint4*)Bfrag)[t + 1024];

    // A stream base: row = row0 + wv*16 + (lane&15), k0 = (lane>>4)*8
    const float4* ap4 = (const float4*)
        (h + (row0 + wv * 16 + (lane & 15)) * DIN + ((lane >> 4) << 3));
    // chunk c: float4 indices c*8 and c*8+1

    f32x4 acc0 = {0.f,0.f,0.f,0.f}, acc1 = {0.f,0.f,0.f,0.f};
    const uint4 z4 = make_uint4(0u, 0u, 0u, 0u);

    // 2-deep prologue (issued AFTER B loads -> in-order FIFO keeps them live)
    float4 pa0 = ap4[0], pb0 = ap4[1];
    float4 pa1 = ap4[8], pb1 = ap4[9];

    // barrier: drain LDS writes only (lgkm); A loads stay in flight
    asm volatile("s_waitcnt lgkmcnt(0)" ::: "memory");
    __builtin_amdgcn_s_barrier();

    #pragma unroll
    for (int c = 0; c < 16; ++c) {
        float4 x0, x1;
        if (c & 1) { x0 = pa1; x1 = pb1; }
        else       { x0 = pa0; x1 = pb0; }
        if (c + 2 < 16) {                 // refill consumed stage
            if (c & 1) { pa1 = ap4[(c + 2) * 8]; pb1 = ap4[(c + 2) * 8 + 1]; }
            else       { pa0 = ap4[(c + 2) * 8]; pb0 = ap4[(c + 2) * 8 + 1]; }
        }
        unsigned e0 = (unsigned)f2bf(x0.x) | ((unsigned)f2bf(x0.y) << 16);
        unsigned e1 = (unsigned)f2bf(x0.z) | ((unsigned)f2bf(x0.w) << 16);
        unsigned e2 = (unsigned)f2bf(x1.x) | ((unsigned)f2bf(x1.y) << 16);
        unsigned e3 = (unsigned)f2bf(x1.z) | ((unsigned)f2bf(x1.w) << 16);
        uint4 au = make_uint4(e0, e1, e2, e3);
        bf16x8 af = __builtin_bit_cast(bf16x8, au);

        uint4 b0 = Bs[c * 64 + lane];
        uint4 b1 = Bs[1024 + c * 16 + ((lane >> 4) << 2) + (lane & 3)];
        if ((lane & 15) >= 4) b1 = z4;

        acc0 = __builtin_amdgcn_mfma_f32_16x16x32_bf16(
            af, __builtin_bit_cast(bf16x8, b0), acc0, 0, 0, 0);
        acc1 = __builtin_amdgcn_mfma_f32_16x16x32_bf16(
            af, __builtin_bit_cast(bf16x8, b1), acc1, 0, 0, 0);
    }

    // epilogue: D-map col=lane&15, row=(lane>>4)*4+p; add bias, transpose
    // through LDS, coalesced float4 stores (320 float4: 256 + 64).
    {
        int col0 = lane & 15;
        int r0   = wv * 16 + ((lane >> 4) << 2);
        float bv0 = bias[col0];
        #pragma unroll
        for (int p = 0; p < 4; ++p)
            scT[(r0 + p) * SCP + col0] = acc0[p] + bv0;
        if (col0 < 4) {
            float bv1 = bias[16 + col0];
            #pragma unroll
            for (int p = 0; p < 4; ++p)
                scT[(r0 + p) * SCP + 16 + col0] = acc1[p] + bv1;
        }
    }
    asm volatile("s_waitcnt lgkmcnt(0)" ::: "memory");
    __builtin_amdgcn_s_barrier();
    {
        float4* dst = (float4*)(buf + row0 * LC);   // 320 float4 per block
        int f0 = t * 4;
        float4 o;
        o.x = scT[((f0 + 0) / 20) * SCP + (f0 + 0) % 20];
        o.y = scT[((f0 + 1) / 20) * SCP + (f0 + 1) % 20];
        o.z = scT[((f0 + 2) / 20) * SCP + (f0 + 2) % 20];
        o.w = scT[((f0 + 3) / 20) * SCP + (f0 + 3) % 20];
        dst[t] = o;
        if (t < 64) {
            int p = 256 + t, g0 = p * 4;
            float4 o2;
            o2.x = scT[((g0 + 0) / 20) * SCP + (g0 + 0) % 20];
            o2.y = scT[((g0 + 1) / 20) * SCP + (g0 + 1) % 20];
            o2.z = scT[((g0 + 2) / 20) * SCP + (g0 + 2) % 20];
            o2.w = scT[((g0 + 3) / 20) * SCP + (g0 + 3) % 20];
            dst[p] = o2;
        }
    }
}

// ---------------------------------------------------------------------------
// level body (shared by level_kernel and tail_kernel)
// ---------------------------------------------------------------------------
__device__ __forceinline__ void level_body(
    float* __restrict__ buf, const float* __restrict__ et,
    float* __restrict__ out, int bi, int node, int q)
{
    size_t pbase = ((size_t)bi * NNODES + node) * LC;
    size_t lbase = ((size_t)bi * NNODES + 2 * node + 1) * LC;

    float l[LC], r[LC];
    const float4* l4 = (const float4*)(buf + lbase);
    const float4* r4 = (const float4*)(buf + lbase + LC);
    #pragma unroll
    for (int v = 0; v < 5; ++v) {
        float4 lv = l4[v], rv = r4[v];
        l[4*v+0] = lv.x; l[4*v+1] = lv.y; l[4*v+2] = lv.z; l[4*v+3] = lv.w;
        r[4*v+0] = rv.x; r[4*v+1] = rv.y; r[4*v+2] = rv.z; r[4*v+3] = rv.w;
    }
    float maxl = l[0], maxr = r[0];
    #pragma unroll
    for (int i = 1; i < LC; ++i) {
        maxl = fmaxf(maxl, l[i]);
        maxr = fmaxf(maxr, r[i]);
    }
    float el[LC], er[LC];
    #pragma unroll
    for (int i = 0; i < LC; ++i) {
        el[i] = __expf(l[i] - maxl);
        er[i] = __expf(r[i] - maxr);
    }

    const float4* etq = (const float4*)(et + q * ET_PAD);
    float s = 0.f;
    #pragma unroll
    for (int i = 0; i < LC; ++i) {
        float4 e0 = etq[i*5+0], e1 = etq[i*5+1], e2 = etq[i*5+2],
               e3 = etq[i*5+3], e4 = etq[i*5+4];
        float d0 = 0.f, d1 = 0.f;
        d0 = fmaf(e0.x, er[0],  d0); d1 = fmaf(e0.y, er[1],  d1);
        d0 = fmaf(e0.z, er[2],  d0); d1 = fmaf(e0.w, er[3],  d1);
        d0 = fmaf(e1.x, er[4],  d0); d1 = fmaf(e1.y, er[5],  d1);
        d0 = fmaf(e1.z, er[6],  d0); d1 = fmaf(e1.w, er[7],  d1);
        d0 = fmaf(e2.x, er[8],  d0); d1 = fmaf(e2.y, er[9],  d1);
        d0 = fmaf(e2.z, er[10], d0); d1 = fmaf(e2.w, er[11], d1);
        d0 = fmaf(e3.x, er[12], d0); d1 = fmaf(e3.y, er[13], d1);
        d0 = fmaf(e3.z, er[14], d0); d1 = fmaf(e3.w, er[15], d1);
        d0 = fmaf(e4.x, er[16], d0); d1 = fmaf(e4.y, er[17], d1);
        d0 = fmaf(e4.z, er[18], d0); d1 = fmaf(e4.w, er[19], d1);
        s = fmaf(el[i], d0 + d1, s);
    }

    float val = buf[pbase + q] + maxl + maxr + __logf(s);
    buf[pbase + q] = val;
    if (out) out[(size_t)bi * LC + q] = val;
}

// ---------------------------------------------------------------------------
// level: one launch per level for d = 8, 7
// ---------------------------------------------------------------------------
__global__ __launch_bounds__(256) void level_kernel(
    float* __restrict__ buf, const float* __restrict__ ETg,
    int start, int count)
{
    __shared__ float et[LC * ET_PAD];
    for (int idx = threadIdx.x; idx < LC * ET_PAD / 4; idx += 256)
        ((float4*)et)[idx] = ((const float4*)ETg)[idx];
    __syncthreads();

    int t  = blockIdx.x * 256 + threadIdx.x;
    int pj = t / LC;
    int q  = t - pj * LC;
    if (pj >= NB * count) return;
    int bi   = pj / count;
    int node = start + (pj - bi * count);
    level_body(buf, et, nullptr, bi, node, q);
}

// ---------------------------------------------------------------------------
// tail: levels d = 6..0 fused, one block per batch element
// ---------------------------------------------------------------------------
__global__ __launch_bounds__(640) void tail_kernel(
    float* __restrict__ buf, const float* __restrict__ ETg,
    float* __restrict__ out)
{
    __shared__ float et[LC * ET_PAD];
    for (int idx = threadIdx.x; idx < LC * ET_PAD / 4; idx += 640)
        ((float4*)et)[idx] = ((const float4*)ETg)[idx];
    __syncthreads();

    const int bi = blockIdx.x;
    for (int d = 6; d >= 0; --d) {
        int count = 1 << d;
        int start = count - 1;
        int total = count * LC;
        for (int base = 0; base < total; base += 640) {
            int idx = base + (int)threadIdx.x;
            if (idx < total) {
                int node = start + idx / LC;
                int q    = idx % LC;
                level_body(buf, et, (d == 0) ? out : nullptr, bi, node, q);
            }
        }
        __syncthreads();
    }
}

// ---------------------------------------------------------------------------
extern "C" void kernel_launch(void* const* d_in, const int* in_sizes, int n_in,
                              void* d_out, int out_size, void* d_ws, size_t ws_size,
                              hipStream_t stream)
{
    const float* h     = (const float*)d_in[0];
    const float* W     = (const float*)d_in[1];
    const float* bias  = (const float*)d_in[2];
    const float* trans = (const float*)d_in[3];

    char* ws = (char*)d_ws;
    float* ET    = (float*)(ws);                     // 32320 B (pad to 32768)
    u16*   Bfrag = (u16*)(ws + 32768);               // 20480 B (pad to 24576)
    float* buf   = (float*)(ws + 32768 + 24576);     // 65472*20*4 B

    // 1. precompute exp(trans) reindexed + compact B fragments
    prep_kernel<<<32, 256, 0, stream>>>(trans, W, ET, Bfrag);

    // 2. sw = h@W + b  (MFMA bf16, barrier-free K-loop, 1023 blocks)
    gemm_kernel<<<NROWS / BM, 256, 0, stream>>>(h, Bfrag, bias, buf);

    // 3. inside pass: d=8,7 separate, d=6..0 fused
    for (int d = 8; d >= 7; --d) {
        int count = 1 << d;
        int start = count - 1;
        int T = NB * count * LC;
        level_kernel<<<(T + 255) / 256, 256, 0, stream>>>(buf, ET, start, count);
    }
    tail_kernel<<<NB, 640, 0, stream>>>(buf, ET, (float*)d_out);
}

// Round 12
// 73.696 us; speedup vs baseline: 1.0057x; 1.0057x over previous
//
#include <hip/hip_runtime.h>
#include <hip/hip_bf16.h>
#include <math.h>

#define NB      64      // batch
#define NNODES  1023    // 2*512-1
#define LC      20      // L*C = 5*4
#define DIN     512
#define NROWS   (NB * NNODES)   // 65472 = 1023 * 64 exactly
#define ET_PAD  404     // 400 + 4 pad

#define BM      64              // rows per gemm block (grid 1023)
#define SCP     21              // epilogue scratch stride

typedef unsigned short u16;
typedef short bf16x8 __attribute__((ext_vector_type(8)));
typedef float f32x4  __attribute__((ext_vector_type(4)));

__device__ __forceinline__ u16 f2bf(float f) {   // RNE f32 -> bf16 bits
    unsigned x = __float_as_uint(f);
    return (u16)((x + 0x7FFFu + ((x >> 16) & 1u)) >> 16);
}

// async global->LDS, 16B per lane: dest = lds_base(uniform) + lane*16
__device__ __forceinline__ void gload_lds16(const void* g, void* l) {
    __builtin_amdgcn_global_load_lds(
        (const __attribute__((address_space(1))) unsigned*)g,
        (__attribute__((address_space(3))) unsigned*)l, 16, 0, 0);
}

// ---------------------------------------------------------------------------
// prep: ET (exp(trans) reindexed) + B fragments, compact layout (1280 uint4):
//  [0,1024):   nf=0 full:   idx = cg*64 + lane -> W[cg*32+(lane>>4)*8+j][lane&15]
//  [1024,1280): nf=1 compact: idx = 1024 + cg*16 + g*4 + c -> W[cg*32+g*8+j][16+c]
// ---------------------------------------------------------------------------
__global__ __launch_bounds__(256) void prep_kernel(
    const float* __restrict__ trans, const float* __restrict__ W,
    float* __restrict__ ET, u16* __restrict__ Bfrag)
{
    int t = blockIdx.x * 256 + threadIdx.x;
    if (t < 8000) {
        int q   = t % 20;
        int rem = t / 20;
        int j   = rem % 20;
        int i   = rem / 20;
        int ll = i >> 2, cl = i & 3;
        int lr = j >> 2, cr = j & 3;
        int lp = q >> 2, cp = q & 3;
        int src = ((((lp * 5 + ll) * 5 + lr) * 4 + cp) * 4 + cl) * 4 + cr;
        ET[q * ET_PAD + i * 20 + j] = expf(trans[src]);
    }
    if (t < 1280) {
        int col, kb;
        if (t < 1024) {
            int lane = t & 63, cg = t >> 6;
            col = lane & 15;
            kb  = cg * 32 + ((lane >> 4) & 3) * 8;
        } else {
            int idx = t - 1024;
            int cg = idx >> 4, g = (idx >> 2) & 3, c = idx & 3;
            col = 16 + c;
            kb  = cg * 32 + g * 8;
        }
        unsigned e[8];
        #pragma unroll
        for (int j = 0; j < 8; ++j)
            e[j] = (unsigned)f2bf(W[(kb + j) * LC + col]);
        uint4 v;
        v.x = e[0] | (e[1] << 16); v.y = e[2] | (e[3] << 16);
        v.z = e[4] | (e[5] << 16); v.w = e[6] | (e[7] << 16);
        ((uint4*)Bfrag)[t] = v;
    }
}

// ---------------------------------------------------------------------------
// gemm via mfma_f32_16x16x32_bf16 with global_load_lds A-staging (m97 style):
// A: raw f32 -> LDS via global_load_lds width16, TRIPLE-buffered (8KB each),
//    2-ahead pipeline with counted s_waitcnt vmcnt(2) (never drains).
//    Source-swizzled (j' = j ^ (r&7)): linear LDS dest, pre-swizzled global
//    source, same XOR on ds_read -> 2-way (free) bank access.
// B: compact fragments staged via global_load_lds once (20KB).
// Per phase/wave: 2 gl_lds + 4 ds_read_b128 + cvt VALU + 2 MFMA.
// ---------------------------------------------------------------------------
__global__ __launch_bounds__(256, 3) void gemm_kernel(
    const float* __restrict__ h, const u16* __restrict__ Bfrag,
    const float* __restrict__ bias, float* __restrict__ buf)
{
    __shared__ float As[3][BM][32];     // 3 x 8KB, [row][32 f32], swizzled content
    __shared__ uint4 Bs[1280];          // 20KB B fragments
    __shared__ float scT[BM * SCP];     // 5.25KB epilogue transpose
    const int t    = threadIdx.x;
    const int lane = t & 63;
    const int wv   = t >> 6;
    const size_t row0 = (size_t)blockIdx.x * BM;

    // --- B stage: 20 x 1KB slices via global_load_lds (5 per wave) ---
    {
        const char* bsrc = (const char*)Bfrag;
        char* bdst = (char*)Bs;
        #pragma unroll
        for (int k = 0; k < 5; ++k) {
            int slice = wv * 5 + k;
            gload_lds16(bsrc + slice * 1024 + lane * 16, bdst + slice * 1024);
        }
    }

    // --- A staging geometry (2 slices/thread/chunk) ---
    // slot s = i*256 + t; r = s>>3; j' = s&7; source k-unit = j'^(r&7)
    const int s0 = t, s1 = t + 256;
    const int r0s = s0 >> 3, j0s = s0 & 7;
    const int r1s = s1 >> 3, j1s = s1 & 7;
    const float* g0 = h + (row0 + r0s) * DIN + ((j0s ^ (r0s & 7)) << 2);
    const float* g1 = h + (row0 + r1s) * DIN + ((j1s ^ (r1s & 7)) << 2);
    char* const asB = (char*)As;                 // buffer b at asB + b*8192
    const int d0 = (0 * 256 + wv * 64) * 16;     // wave-uniform dest offsets
    const int d1 = (1 * 256 + wv * 64) * 16;

#define STAGE(B, C) {                                                         \
    char* _lb = asB + (B) * 8192;                                             \
    gload_lds16(g0 + (C) * 32, _lb + d0);                                     \
    gload_lds16(g1 + (C) * 32, _lb + d1); }

    // prologue: B(5/wave) + A c0 -> buf0 + A c1 -> buf1; keep c1 in flight
    STAGE(0, 0)
    STAGE(1, 1)
    asm volatile("s_waitcnt vmcnt(2) lgkmcnt(0)" ::: "memory");
    __builtin_amdgcn_s_barrier();

    f32x4 acc0 = {0.f,0.f,0.f,0.f}, acc1 = {0.f,0.f,0.f,0.f};
    const uint4 z4 = make_uint4(0u, 0u, 0u, 0u);
    const int R  = wv * 16 + (lane & 15);
    const int xr = R & 7;
    const int jb = (lane >> 4) << 1;             // 0,2,4,6
    const int aoff0 = R * 128 + ((jb ^ xr) << 4);
    const int aoff1 = R * 128 + (((jb | 1) ^ xr) << 4);

    #pragma unroll
    for (int c = 0; c < 16; ++c) {
        const int cur = c % 3;
        if (c + 2 < 16) {
            const int nxt = (c + 2) % 3;
            STAGE(nxt, c + 2)
        }
        // A-frag: two swizzled b128 reads + cvt to bf16x8
        const char* ab = asB + cur * 8192;
        float4 x0 = *(const float4*)(ab + aoff0);
        float4 x1 = *(const float4*)(ab + aoff1);
        unsigned e0 = (unsigned)f2bf(x0.x) | ((unsigned)f2bf(x0.y) << 16);
        unsigned e1 = (unsigned)f2bf(x0.z) | ((unsigned)f2bf(x0.w) << 16);
        unsigned e2 = (unsigned)f2bf(x1.x) | ((unsigned)f2bf(x1.y) << 16);
        unsigned e3 = (unsigned)f2bf(x1.z) | ((unsigned)f2bf(x1.w) << 16);
        uint4 au = make_uint4(e0, e1, e2, e3);
        bf16x8 af = __builtin_bit_cast(bf16x8, au);

        uint4 b0 = Bs[c * 64 + lane];
        uint4 b1 = Bs[1024 + c * 16 + ((lane >> 4) << 2) + (lane & 3)];
        if ((lane & 15) >= 4) b1 = z4;

        acc0 = __builtin_amdgcn_mfma_f32_16x16x32_bf16(
            af, __builtin_bit_cast(bf16x8, b0), acc0, 0, 0, 0);
        acc1 = __builtin_amdgcn_mfma_f32_16x16x32_bf16(
            af, __builtin_bit_cast(bf16x8, b1), acc1, 0, 0, 0);

        if (c < 15) {
            if (c + 2 < 16) {   // steady state: keep newest chunk in flight
                asm volatile("s_waitcnt vmcnt(2) lgkmcnt(0)" ::: "memory");
            } else {            // tail: drain (only next chunk outstanding)
                asm volatile("s_waitcnt vmcnt(0) lgkmcnt(0)" ::: "memory");
            }
            __builtin_amdgcn_s_barrier();
        }
    }
#undef STAGE

    // epilogue: D-map col=lane&15, row=(lane>>4)*4+p; add bias, transpose
    // through LDS, coalesced float4 stores (320 float4: 256 + 64).
    {
        int col0 = lane & 15;
        int r0   = wv * 16 + ((lane >> 4) << 2);
        float bv0 = bias[col0];
        #pragma unroll
        for (int p = 0; p < 4; ++p)
            scT[(r0 + p) * SCP + col0] = acc0[p] + bv0;
        if (col0 < 4) {
            float bv1 = bias[16 + col0];
            #pragma unroll
            for (int p = 0; p < 4; ++p)
                scT[(r0 + p) * SCP + 16 + col0] = acc1[p] + bv1;
        }
    }
    __syncthreads();
    {
        float4* dst = (float4*)(buf + row0 * LC);   // 320 float4 per block
        int f0 = t * 4;
        float4 o;
        o.x = scT[((f0 + 0) / 20) * SCP + (f0 + 0) % 20];
        o.y = scT[((f0 + 1) / 20) * SCP + (f0 + 1) % 20];
        o.z = scT[((f0 + 2) / 20) * SCP + (f0 + 2) % 20];
        o.w = scT[((f0 + 3) / 20) * SCP + (f0 + 3) % 20];
        dst[t] = o;
        if (t < 64) {
            int p = 256 + t, g4 = p * 4;
            float4 o2;
            o2.x = scT[((g4 + 0) / 20) * SCP + (g4 + 0) % 20];
            o2.y = scT[((g4 + 1) / 20) * SCP + (g4 + 1) % 20];
            o2.z = scT[((g4 + 2) / 20) * SCP + (g4 + 2) % 20];
            o2.w = scT[((g4 + 3) / 20) * SCP + (g4 + 3) % 20];
            dst[p] = o2;
        }
    }
}

// ---------------------------------------------------------------------------
// level body (shared by level_kernel and tail_kernel)
// ---------------------------------------------------------------------------
__device__ __forceinline__ void level_body(
    float* __restrict__ buf, const float* __restrict__ et,
    float* __restrict__ out, int bi, int node, int q)
{
    size_t pbase = ((size_t)bi * NNODES + node) * LC;
    size_t lbase = ((size_t)bi * NNODES + 2 * node + 1) * LC;

    float l[LC], r[LC];
    const float4* l4 = (const float4*)(buf + lbase);
    const float4* r4 = (const float4*)(buf + lbase + LC);
    #pragma unroll
    for (int v = 0; v < 5; ++v) {
        float4 lv = l4[v], rv = r4[v];
        l[4*v+0] = lv.x; l[4*v+1] = lv.y; l[4*v+2] = lv.z; l[4*v+3] = lv.w;
        r[4*v+0] = rv.x; r[4*v+1] = rv.y; r[4*v+2] = rv.z; r[4*v+3] = rv.w;
    }
    float maxl = l[0], maxr = r[0];
    #pragma unroll
    for (int i = 1; i < LC; ++i) {
        maxl = fmaxf(maxl, l[i]);
        maxr = fmaxf(maxr, r[i]);
    }
    float el[LC], er[LC];
    #pragma unroll
    for (int i = 0; i < LC; ++i) {
        el[i] = __expf(l[i] - maxl);
        er[i] = __expf(r[i] - maxr);
    }

    const float4* etq = (const float4*)(et + q * ET_PAD);
    float s = 0.f;
    #pragma unroll
    for (int i = 0; i < LC; ++i) {
        float4 e0 = etq[i*5+0], e1 = etq[i*5+1], e2 = etq[i*5+2],
               e3 = etq[i*5+3], e4 = etq[i*5+4];
        float d0 = 0.f, d1 = 0.f;
        d0 = fmaf(e0.x, er[0],  d0); d1 = fmaf(e0.y, er[1],  d1);
        d0 = fmaf(e0.z, er[2],  d0); d1 = fmaf(e0.w, er[3],  d1);
        d0 = fmaf(e1.x, er[4],  d0); d1 = fmaf(e1.y, er[5],  d1);
        d0 = fmaf(e1.z, er[6],  d0); d1 = fmaf(e1.w, er[7],  d1);
        d0 = fmaf(e2.x, er[8],  d0); d1 = fmaf(e2.y, er[9],  d1);
        d0 = fmaf(e2.z, er[10], d0); d1 = fmaf(e2.w, er[11], d1);
        d0 = fmaf(e3.x, er[12], d0); d1 = fmaf(e3.y, er[13], d1);
        d0 = fmaf(e3.z, er[14], d0); d1 = fmaf(e3.w, er[15], d1);
        d0 = fmaf(e4.x, er[16], d0); d1 = fmaf(e4.y, er[17], d1);
        d0 = fmaf(e4.z, er[18], d0); d1 = fmaf(e4.w, er[19], d1);
        s = fmaf(el[i], d0 + d1, s);
    }

    float val = buf[pbase + q] + maxl + maxr + __logf(s);
    buf[pbase + q] = val;
    if (out) out[(size_t)bi * LC + q] = val;
}

// ---------------------------------------------------------------------------
// level: one launch per level for d = 8, 7
// ---------------------------------------------------------------------------
__global__ __launch_bounds__(256) void level_kernel(
    float* __restrict__ buf, const float* __restrict__ ETg,
    int start, int count)
{
    __shared__ float et[LC * ET_PAD];
    for (int idx = threadIdx.x; idx < LC * ET_PAD / 4; idx += 256)
        ((float4*)et)[idx] = ((const float4*)ETg)[idx];
    __syncthreads();

    int t  = blockIdx.x * 256 + threadIdx.x;
    int pj = t / LC;
    int q  = t - pj * LC;
    if (pj >= NB * count) return;
    int bi   = pj / count;
    int node = start + (pj - bi * count);
    level_body(buf, et, nullptr, bi, node, q);
}

// ---------------------------------------------------------------------------
// tail: levels d = 6..0 fused, one block per batch element
// ---------------------------------------------------------------------------
__global__ __launch_bounds__(640) void tail_kernel(
    float* __restrict__ buf, const float* __restrict__ ETg,
    float* __restrict__ out)
{
    __shared__ float et[LC * ET_PAD];
    for (int idx = threadIdx.x; idx < LC * ET_PAD / 4; idx += 640)
        ((float4*)et)[idx] = ((const float4*)ETg)[idx];
    __syncthreads();

    const int bi = blockIdx.x;
    for (int d = 6; d >= 0; --d) {
        int count = 1 << d;
        int start = count - 1;
        int total = count * LC;
        for (int base = 0; base < total; base += 640) {
            int idx = base + (int)threadIdx.x;
            if (idx < total) {
                int node = start + idx / LC;
                int q    = idx % LC;
                level_body(buf, et, (d == 0) ? out : nullptr, bi, node, q);
            }
        }
        __syncthreads();
    }
}

// ---------------------------------------------------------------------------
extern "C" void kernel_launch(void* const* d_in, const int* in_sizes, int n_in,
                              void* d_out, int out_size, void* d_ws, size_t ws_size,
                              hipStream_t stream)
{
    const float* h     = (const float*)d_in[0];
    const float* W     = (const float*)d_in[1];
    const float* bias  = (const float*)d_in[2];
    const float* trans = (const float*)d_in[3];

    char* ws = (char*)d_ws;
    float* ET    = (float*)(ws);                     // 32320 B (pad to 32768)
    u16*   Bfrag = (u16*)(ws + 32768);               // 20480 B (pad to 24576)
    float* buf   = (float*)(ws + 32768 + 24576);     // 65472*20*4 B

    // 1. precompute exp(trans) reindexed + compact B fragments
    prep_kernel<<<32, 256, 0, stream>>>(trans, W, ET, Bfrag);

    // 2. sw = h@W + b  (MFMA bf16, global_load_lds triple-buffered pipeline)
    gemm_kernel<<<NROWS / BM, 256, 0, stream>>>(h, Bfrag, bias, buf);

    // 3. inside pass: d=8,7 separate, d=6..0 fused
    for (int d = 8; d >= 7; --d) {
        int count = 1 << d;
        int start = count - 1;
        int T = NB * count * LC;
        level_kernel<<<(T + 255) / 256, 256, 0, stream>>>(buf, ET, start, count);
    }
    tail_kernel<<<NB, 640, 0, stream>>>(buf, ET, (float*)d_out);
}